// Round 1
// 249.869 us; speedup vs baseline: 1.0065x; 1.0065x over previous
//
#include <hip/hip_runtime.h>
#include <math.h>

// Problem constants
constexpr int Bc = 2;
constexpr int Sc = 2048;
constexpr int Dc = 1024;
constexpr int Hc = 16;
constexpr int HDc = 64;

// Q pre-scale: attention 1/sqrt(64) folded with log2(e) for exp2-domain softmax
constexpr float QSC = 0.125f * 1.4426950408889634f;

typedef __attribute__((ext_vector_type(8))) short bf16x8;
typedef __attribute__((ext_vector_type(4))) float f32x4;
typedef __attribute__((ext_vector_type(4))) unsigned short us4;
typedef __attribute__((ext_vector_type(2))) unsigned int u32x2;
typedef __attribute__((ext_vector_type(4))) unsigned int u32x4;

// fp32 -> bf16 round-to-nearest-even (returns low 16 bits)
__device__ __forceinline__ unsigned f2bf(float x) {
    unsigned u = __float_as_uint(x);
    return (u + 0x7FFFu + ((u >> 16) & 1u)) >> 16;
}

__device__ __forceinline__ void split2(float x, unsigned short& h, unsigned short& l) {
    unsigned hh = f2bf(x);
    h = (unsigned short)hh;
    l = (unsigned short)f2bf(x - __uint_as_float(hh << 16));
}

// gfx950 cross-lane half-swaps: a=vdst, b=src; both updated.
#if __has_builtin(__builtin_amdgcn_permlane32_swap)
__device__ __forceinline__ void plswap32(unsigned& a, unsigned& b) {
    u32x2 r = __builtin_amdgcn_permlane32_swap(a, b, false, false);
    a = r.x; b = r.y;
}
#else
__device__ __forceinline__ void plswap32(unsigned& a, unsigned& b) {
    asm volatile("v_permlane32_swap_b32 %0, %1" : "+v"(a), "+v"(b));
}
#endif
#if __has_builtin(__builtin_amdgcn_permlane16_swap)
__device__ __forceinline__ void plswap16(unsigned& a, unsigned& b) {
    u32x2 r = __builtin_amdgcn_permlane16_swap(a, b, false, false);
    a = r.x; b = r.y;
}
#else
__device__ __forceinline__ void plswap16(unsigned& a, unsigned& b) {
    asm volatile("v_permlane16_swap_b32 %0, %1" : "+v"(a), "+v"(b));
}
#endif

// exp2 of 4 S-values, packed (truncating) into two bf16-pair words:
// w0 = {bf16(s0) lo, bf16(s1) hi}, w1 = {bf16(s2) lo, bf16(s3) hi}
__device__ __forceinline__ void exppack(const f32x4& sv, unsigned& w0, unsigned& w1) {
    unsigned u0 = __float_as_uint(__builtin_amdgcn_exp2f(sv[0]));
    unsigned u1 = __float_as_uint(__builtin_amdgcn_exp2f(sv[1]));
    unsigned u2 = __float_as_uint(__builtin_amdgcn_exp2f(sv[2]));
    unsigned u3 = __float_as_uint(__builtin_amdgcn_exp2f(sv[3]));
    w0 = __builtin_amdgcn_perm(u1, u0, 0x07060302u);
    w1 = __builtin_amdgcn_perm(u3, u2, 0x07060302u);
}

// ---------------------------------------------------------------------------
// RoPE cos/sin table: [S][32] each, double precision angles.
// ---------------------------------------------------------------------------
__global__ void rope_table(float* __restrict__ ct, float* __restrict__ st_) {
    int id = blockIdx.x * 256 + threadIdx.x;
    int s = id >> 5;
    int i = id & 31;
    double invf = pow(10000.0, -(double)i / 32.0);
    double ang = (double)s * invf;
    ct[id] = (float)cos(ang);
    st_[id] = (float)sin(ang);
}

// ---------------------------------------------------------------------------
// Convert: x -> bf16 hi; Wq/Wk/Wv -> hi; Wo -> hi + lo.
// ---------------------------------------------------------------------------
__global__ void split_xw(const float* __restrict__ x,
                         const float* __restrict__ Wq, const float* __restrict__ Wk,
                         const float* __restrict__ Wv, const float* __restrict__ Wo,
                         unsigned short* __restrict__ xh,
                         unsigned short* __restrict__ whAll, unsigned short* __restrict__ wlAll) {
    int y = blockIdx.y;
    const float* src;
    unsigned short* h;
    unsigned short* l = nullptr;
    int n;
    if (y == 0) { src = x; h = xh; n = 1 << 22; }
    else {
        src = (y == 1) ? Wq : (y == 2) ? Wk : (y == 3) ? Wv : Wo;
        h = whAll + (size_t)(y - 1) * (1 << 20);
        if (y == 4) l = wlAll + (size_t)3 * (1 << 20);
        n = 1 << 20;
    }
    int i = (blockIdx.x * 256 + threadIdx.x) * 4;
    if (i >= n) return;
    float4 v = *(const float4*)(src + i);
    us4 hh;
    ((unsigned short*)&hh)[0] = (unsigned short)f2bf(v.x);
    ((unsigned short*)&hh)[1] = (unsigned short)f2bf(v.y);
    ((unsigned short*)&hh)[2] = (unsigned short)f2bf(v.z);
    ((unsigned short*)&hh)[3] = (unsigned short)f2bf(v.w);
    *(us4*)(h + i) = hh;
    if (l) {
        us4 ll;
        const float* vp = (const float*)&v;
#pragma unroll
        for (int e = 0; e < 4; e++) {
            unsigned short hi = ((unsigned short*)&hh)[e];
            ((unsigned short*)&ll)[e] =
                (unsigned short)f2bf(vp[e] - __uint_as_float((unsigned)hi << 16));
        }
        *(us4*)(l + i) = ll;
    }
}

// ---------------------------------------------------------------------------
// QKV GEMM, bf16 1-product, 128x128 tile, BK=32, dbuf. m-fastest grid.
// Epilogues: z=0 Q (RoPE+QSC row-major), z=1 K (RoPE, [T][kb][tok][8] cells),
//            z=2 V (V^T cells [T][kk(2)][qd(4)][d(64)][tok8] — native K=32
//                   A-operand layout for attention PV)
// ---------------------------------------------------------------------------
__global__ __launch_bounds__(256) void gemm_qkv(
    const unsigned short* __restrict__ Ah,
    const unsigned short* __restrict__ whAll,
    unsigned short* __restrict__ Qh,
    unsigned short* __restrict__ Kh,
    unsigned short* __restrict__ Vh,
    const float* __restrict__ ct, const float* __restrict__ st_) {
    constexpr int K = 1024;
    __shared__ __align__(16) unsigned short AsH[2 * 4096], BsH[2 * 4096];

    const int z = blockIdx.z;
    const unsigned short* Wh = whAll + (size_t)z * (1 << 20);

    const int t = threadIdx.x;
    const int lane = t & 63;
    const int wave = t >> 6;
    const int l = lane & 15;
    const int quad = lane >> 4;
    const int wr = wave >> 1, wc = wave & 1;
    const int m0 = blockIdx.x * 128;
    const int n0 = blockIdx.y * 128;

    const int s_tensor = wave >> 1;
    const int s_rb = wave & 1;
    unsigned short* larr = s_tensor ? BsH : AsH;
    const unsigned short* gbase =
        (s_tensor ? Wh + (size_t)(n0 + s_rb * 64 + lane) * K
                  : Ah + (size_t)(m0 + s_rb * 64 + lane) * K);

    f32x4 acc[4][4];
#pragma unroll
    for (int i = 0; i < 4; i++)
#pragma unroll
        for (int j = 0; j < 4; j++) acc[i][j] = (f32x4){0.f, 0.f, 0.f, 0.f};

#pragma unroll
    for (int q = 0; q < 4; q++)
        __builtin_amdgcn_global_load_lds(
            (const __attribute__((address_space(1))) unsigned int*)(gbase + q * 8),
            (__attribute__((address_space(3))) unsigned int*)(larr + (q * 128 + s_rb * 64) * 8),
            16, 0, 0);

    for (int it = 0; it < 32; ++it) {
        __syncthreads();
        if (it + 1 < 32) {
            const unsigned short* g = gbase + (it + 1) * 32;
            unsigned short* buf = larr + ((it + 1) & 1) * 4096;
#pragma unroll
            for (int q = 0; q < 4; q++)
                __builtin_amdgcn_global_load_lds(
                    (const __attribute__((address_space(1))) unsigned int*)(g + q * 8),
                    (__attribute__((address_space(3))) unsigned int*)(buf + (q * 128 + s_rb * 64) * 8),
                    16, 0, 0);
        }
        const unsigned short* a = AsH + (it & 1) * 4096;
        const unsigned short* bb = BsH + (it & 1) * 4096;
        bf16x8 ah[4], bh[4];
#pragma unroll
        for (int i = 0; i < 4; i++) {
            ah[i] = *(const bf16x8*)&a[(quad * 128 + wr * 64 + i * 16 + l) * 8];
            bh[i] = *(const bf16x8*)&bb[(quad * 128 + wc * 64 + i * 16 + l) * 8];
        }
#pragma unroll
        for (int i = 0; i < 4; i++)
#pragma unroll
            for (int j = 0; j < 4; j++)
                acc[i][j] = __builtin_amdgcn_mfma_f32_16x16x32_bf16(ah[i], bh[j], acc[i][j], 0, 0, 0);
    }

    // ---- fused epilogue ----
    const int hcol = ((n0 + wc * 64) >> 6);   // head index 0..15
    if (z == 2) {
        // V^T cells, K=32 A-operand layout:
        //   off = ((kk*4 + qd)*64 + d)*8 + tj, tok64 = kk*32 + qd*8 + tj
        // acc[i][jj][r]: tok64 = i*16 + quad*4 + r, d = jj*16 + l
#pragma unroll
        for (int i = 0; i < 4; i++) {
            int m_base = m0 + wr * 64 + i * 16 + quad * 4;
            int bbk = m_base >> 11;
            int T = (m_base & (Sc - 1)) >> 6;
            int kk = i >> 1;
            int qd = ((i & 1) << 1) | (quad >> 1);
            int tj = (quad & 1) * 4;
            size_t tilebase = (((size_t)(bbk * Hc + hcol)) * 32 + T) * 4096;
#pragma unroll
            for (int jj = 0; jj < 4; jj++) {
                int d = jj * 16 + l;
                size_t off = tilebase + (size_t)(((kk * 4 + qd) * 64 + d) * 8 + tj);
                us4 v4;
#pragma unroll
                for (int r = 0; r < 4; r++)
                    ((unsigned short*)&v4)[r] = (unsigned short)f2bf(acc[i][jj][r]);
                *(us4*)(Vh + off) = v4;
            }
        }
    } else {
#pragma unroll
        for (int i = 0; i < 4; i++)
#pragma unroll
            for (int r = 0; r < 4; r++) {
                int m = m0 + wr * 64 + i * 16 + quad * 4 + r;
                int bbk = m >> 11, s = m & (Sc - 1);
#pragma unroll
                for (int jp = 0; jp < 2; jp++) {
                    int d = jp * 16 + l;                       // 0..31
                    float cs = ct[s * 32 + d];
                    float sn = st_[s * 32 + d];
                    float x0 = acc[i][jp][r];
                    float x1 = acc[i][jp + 2][r];
                    float y0 = x0 * cs - x1 * sn;
                    float y1 = x1 * cs + x0 * sn;
                    if (z == 0) {
                        size_t rowb = (((size_t)(bbk * Hc + hcol)) * Sc + s) * HDc;
                        Qh[rowb + d]      = (unsigned short)f2bf(y0 * QSC);
                        Qh[rowb + d + 32] = (unsigned short)f2bf(y1 * QSC);
                    } else {
                        int T = s >> 6, tok = s & 63;
                        size_t tb = (((size_t)(bbk * Hc + hcol)) * 32 + T) * 8;
                        size_t off0 = ((tb + (d >> 3)) * 64 + tok) * 8 + (d & 7);
                        size_t off1 = ((tb + (d >> 3) + 4) * 64 + tok) * 8 + (d & 7);
                        Kh[off0] = (unsigned short)f2bf(y0);
                        Kh[off1] = (unsigned short)f2bf(y1);
                    }
                }
            }
    }
}

// ---------------------------------------------------------------------------
// MFMA flash attention v8: all-K=32 MFMA.
// 64 q/block, 2 waves x 2 bands -> grid 1024 = 4 blocks/CU.
// P^T K=32 B-fragments built in-register via permlane32/16_swap; PV and
// row-sum use mfma_f32_16x16x32_bf16 (no legacy K=16 MFMA anywhere).
// ---------------------------------------------------------------------------
__global__ __launch_bounds__(128) void attn7(
    const unsigned short* __restrict__ Qh,
    const unsigned short* __restrict__ Kh,
    const unsigned short* __restrict__ Vh,
    unsigned short* __restrict__ AOh, unsigned short* __restrict__ AOl) {
    __shared__ __align__(16) unsigned short KsH[2 * 4096], VtH[2 * 4096];

    const int t = threadIdx.x;
    const int lane = t & 63;
    const int wave = t >> 6;               // 0..1
    const int l = lane & 15;
    const int quad = lane >> 4;
    const int id = blockIdx.x;             // 0..1023
    const int bh = (id & 7) * 4 + (id >> 8);   // XCD-clustered (4 bh / XCD)
    const int qt = (id >> 3) & 31;
    const int q0 = qt * 64;
    const int b = bh >> 4;
    const int hh = bh & 15;

    const bf16x8 ONES8 = {(short)0x3F80, (short)0x3F80, (short)0x3F80, (short)0x3F80,
                          (short)0x3F80, (short)0x3F80, (short)0x3F80, (short)0x3F80};

    // Q fragments (B operand: n=q=lane&15, k=d=quad*8+j); band bnd -> rows
    // q0 + bnd*32 + wave*16 + l
    bf16x8 qf[2][2];
#pragma unroll
    for (int bnd = 0; bnd < 2; bnd++) {
        size_t rowb = ((size_t)bh * Sc + q0 + bnd * 32 + wave * 16 + l) * HDc;
#pragma unroll
        for (int ks = 0; ks < 2; ks++)
            qf[bnd][ks] = *(const bf16x8*)(Qh + rowb + ks * 32 + quad * 8);
    }

    f32x4 o[2][4], lac[2];
#pragma unroll
    for (int bnd = 0; bnd < 2; bnd++) {
        lac[bnd] = (f32x4){0.f, 0.f, 0.f, 0.f};
#pragma unroll
        for (int i = 0; i < 4; i++) o[bnd][i] = (f32x4){0.f, 0.f, 0.f, 0.f};
    }

    // staging: wave 0 -> K, wave 1 -> V; 8 chunks of 512 elems each.
    unsigned short* larr = wave ? VtH : KsH;
    const unsigned short* gB = (wave ? Vh : Kh) + (size_t)bh * Sc * HDc + lane * 8;

#pragma unroll
    for (int q = 0; q < 8; q++)
        __builtin_amdgcn_global_load_lds(
            (const __attribute__((address_space(1))) unsigned int*)(gB + q * 512),
            (__attribute__((address_space(3))) unsigned int*)(larr + q * 512),
            16, 0, 0);

    for (int kt = 0; kt < 32; kt++) {
        __syncthreads();
        if (kt + 1 < 32) {
            const unsigned short* g = gB + (size_t)(kt + 1) * 4096;
            unsigned short* buf = larr + ((kt + 1) & 1) * 4096;
#pragma unroll
            for (int q = 0; q < 8; q++)
                __builtin_amdgcn_global_load_lds(
                    (const __attribute__((address_space(1))) unsigned int*)(g + q * 512),
                    (__attribute__((address_space(3))) unsigned int*)(buf + q * 512),
                    16, 0, 0);
        }
        const unsigned short* Kbuf = KsH + (kt & 1) * 4096;
        const unsigned short* Vbuf = VtH + (kt & 1) * 4096;

        // ---- S^T = K @ Q^T: A=K frag (m=tok), B=Q frag (n=q) ----
        f32x4 s[2][4];
#pragma unroll
        for (int bnd = 0; bnd < 2; bnd++)
#pragma unroll
            for (int tt = 0; tt < 4; tt++) s[bnd][tt] = (f32x4){0.f, 0.f, 0.f, 0.f};
#pragma unroll
        for (int ks = 0; ks < 2; ks++)
#pragma unroll
            for (int tt = 0; tt < 4; tt++) {
                bf16x8 kf = *(const bf16x8*)&Kbuf[((ks * 4 + quad) * 64 + tt * 16 + l) * 8];
                s[0][tt] = __builtin_amdgcn_mfma_f32_16x16x32_bf16(kf, qf[0][ks], s[0][tt], 0, 0, 0);
                s[1][tt] = __builtin_amdgcn_mfma_f32_16x16x32_bf16(kf, qf[1][ks], s[1][tt], 0, 0, 0);
            }

        // ---- P^T = exp2(S^T), packed + permlane-transposed into K=32
        //      B-operand fragments (tokens quad*8+j contiguous per lane) ----
        bf16x8 pf[2][2];
#pragma unroll
        for (int bnd = 0; bnd < 2; bnd++)
#pragma unroll
            for (int ttp = 0; ttp < 2; ttp++) {
                unsigned A0, A1, B0, B1;
                exppack(s[bnd][2 * ttp], A0, A1);       // tokens ttp*32 + quad*4 + {0..3}
                exppack(s[bnd][2 * ttp + 1], B0, B1);   // tokens ttp*32 + 16 + quad*4 + {0..3}
                plswap32(A0, B0);   // A0: q01=A0@q01, q23=B0@q01 ; B0: q01=A0@q23, q23=B0@q23
                plswap16(A0, B0);   // A0 -> frag word0, B0 -> frag word2
                plswap32(A1, B1);
                plswap16(A1, B1);   // A1 -> frag word1, B1 -> frag word3
                u32x4 fw = {A0, A1, B0, B1};
                bf16x8 p8 = __builtin_bit_cast(bf16x8, fw);
                pf[bnd][ttp] = p8;
                lac[bnd] = __builtin_amdgcn_mfma_f32_16x16x32_bf16(ONES8, p8, lac[bnd], 0, 0, 0);
            }

        // ---- O^T += V^T @ P^T (K=32; V frags shared across bands) ----
#pragma unroll
        for (int kk = 0; kk < 2; kk++)
#pragma unroll
            for (int dd = 0; dd < 4; dd++) {
                bf16x8 vf = *(const bf16x8*)
                    &Vbuf[(size_t)((kk * 4 + quad) * 64 + dd * 16 + l) * 8];
                o[0][dd] = __builtin_amdgcn_mfma_f32_16x16x32_bf16(vf, pf[0][kk], o[0][dd], 0, 0, 0);
                o[1][dd] = __builtin_amdgcn_mfma_f32_16x16x32_bf16(vf, pf[1][kk], o[1][dd], 0, 0, 0);
            }
    }

    // ---- epilogue: O^T frag: col q = lane&15, row d = dd*16 + quad*4 + r ----
#pragma unroll
    for (int bnd = 0; bnd < 2; bnd++) {
        float inv = 1.f / lac[bnd][0];   // all 4 regs equal (ONES-A rows identical)
        int q = q0 + bnd * 32 + wave * 16 + l;
        size_t rowb = ((size_t)b * Sc + q) * Dc + hh * HDc + quad * 4;
#pragma unroll
        for (int dd = 0; dd < 4; dd++) {
            us4 h4, l4;
#pragma unroll
            for (int r = 0; r < 4; r++)
                split2(o[bnd][dd][r] * inv,
                       ((unsigned short*)&h4)[r], ((unsigned short*)&l4)[r]);
            *(us4*)(AOh + rowb + dd * 16) = h4;
            *(us4*)(AOl + rowb + dd * 16) = l4;
        }
    }
}

// ---------------------------------------------------------------------------
// Output projection GEMM (MFMA split-bf16 3-product, dbuf), 128x128, fp32 out.
// ---------------------------------------------------------------------------
__global__ __launch_bounds__(256) void gemm_out(
    const unsigned short* __restrict__ Ah, const unsigned short* __restrict__ Al,
    const unsigned short* __restrict__ Wh, const unsigned short* __restrict__ Wl,
    float* __restrict__ C) {
    constexpr int K = 1024;
    __shared__ __align__(16) unsigned short AsH[2 * 4096], AsL[2 * 4096],
                                            BsH[2 * 4096], BsL[2 * 4096];

    const int t = threadIdx.x;
    const int lane = t & 63;
    const int wave = t >> 6;
    const int l = lane & 15;
    const int quad = lane >> 4;
    const int wr = wave >> 1, wc = wave & 1;
    const int m0 = blockIdx.x * 128;   // m fastest -> XCD A-locality
    const int n0 = blockIdx.y * 128;

    // staging: wave 0 = A-hi, 1 = A-lo, 2 = B-hi, 3 = B-lo; 8 jobs each.
    unsigned short* larr = (wave == 0) ? AsH : (wave == 1) ? AsL : (wave == 2) ? BsH : BsL;
    const unsigned short* garr = (wave == 0) ? Ah : (wave == 1) ? Al : (wave == 2) ? Wh : Wl;
    const int t0 = (wave < 2) ? m0 : n0;

    const unsigned short* gsrc[8];
    int ldst[8];
#pragma unroll
    for (int q = 0; q < 8; q++) {
        int rb = q >> 2;
        int kb = q & 3;
        gsrc[q] = garr + (size_t)(t0 + rb * 64 + lane) * K + kb * 8;
        ldst[q] = (kb * 128 + rb * 64) * 8;
    }

    f32x4 acc[4][4];
#pragma unroll
    for (int i = 0; i < 4; i++)
#pragma unroll
        for (int j = 0; j < 4; j++) acc[i][j] = (f32x4){0.f, 0.f, 0.f, 0.f};

#pragma unroll
    for (int q = 0; q < 8; q++)
        __builtin_amdgcn_global_load_lds(
            (const __attribute__((address_space(1))) unsigned int*)gsrc[q],
            (__attribute__((address_space(3))) unsigned int*)(larr + ldst[q]), 16, 0, 0);

    for (int it = 0; it < 32; ++it) {
        __syncthreads();
        if (it + 1 < 32) {
            unsigned short* buf = larr + ((it + 1) & 1) * 4096;
            int koff = (it + 1) * 32;
#pragma unroll
            for (int q = 0; q < 8; q++)
                __builtin_amdgcn_global_load_lds(
                    (const __attribute__((address_space(1))) unsigned int*)(gsrc[q] + koff),
                    (__attribute__((address_space(3))) unsigned int*)(buf + ldst[q]), 16, 0, 0);
        }
        const int bo = (it & 1) * 4096;
        bf16x8 ah[4], al[4], bh[4], bl[4];
#pragma unroll
        for (int i = 0; i < 4; i++) {
            int ra = bo + (quad * 128 + wr * 64 + i * 16 + l) * 8;
            ah[i] = *(const bf16x8*)&AsH[ra];
            al[i] = *(const bf16x8*)&AsL[ra];
            int rb2 = bo + (quad * 128 + wc * 64 + i * 16 + l) * 8;
            bh[i] = *(const bf16x8*)&BsH[rb2];
            bl[i] = *(const bf16x8*)&BsL[rb2];
        }
#pragma unroll
        for (int i = 0; i < 4; i++)
#pragma unroll
            for (int j = 0; j < 4; j++) {
                acc[i][j] = __builtin_amdgcn_mfma_f32_16x16x32_bf16(ah[i], bh[j], acc[i][j], 0, 0, 0);
                acc[i][j] = __builtin_amdgcn_mfma_f32_16x16x32_bf16(al[i], bh[j], acc[i][j], 0, 0, 0);
                acc[i][j] = __builtin_amdgcn_mfma_f32_16x16x32_bf16(ah[i], bl[j], acc[i][j], 0, 0, 0);
            }
    }

#pragma unroll
    for (int i = 0; i < 4; i++)
#pragma unroll
        for (int j = 0; j < 4; j++)
#pragma unroll
            for (int r = 0; r < 4; r++) {
                int m = m0 + wr * 64 + i * 16 + quad * 4 + r;
                int n = n0 + wc * 64 + j * 16 + l;
                C[(size_t)m * Dc + n] = acc[i][j][r];
            }
}

// ---------------------------------------------------------------------------
extern "C" void kernel_launch(void* const* d_in, const int* in_sizes, int n_in,
                              void* d_out, int out_size, void* d_ws, size_t ws_size,
                              hipStream_t stream) {
    const float* x  = (const float*)d_in[0];
    const float* Wq = (const float*)d_in[1];
    const float* Wk = (const float*)d_in[2];
    const float* Wv = (const float*)d_in[3];
    const float* Wo = (const float*)d_in[4];
    float* out = (float*)d_out;

    unsigned short* usw = (unsigned short*)d_ws;
    const size_t M4 = (size_t)1 << 22;   // 4M elements
    unsigned short* whAll = usw;                 // 4 x 1M weights hi
    unsigned short* wlAll = usw + M4;            // lo (only Wo slot used)
    unsigned short* xh = usw + 2 * M4;           // x hi (later AOh)
    unsigned short* xl = usw + 3 * M4;           // later AOl
    unsigned short* Qh = usw + 4 * M4;
    unsigned short* Kh = usw + 5 * M4;
    unsigned short* Vh = usw + 6 * M4;
    float* ct = (float*)(usw + 7 * M4);
    float* st_ = ct + (size_t)Sc * 32;
    unsigned short* AOh = xh;   // x dead after QKV GEMM
    unsigned short* AOl = xl;

    // 1. RoPE table
    rope_table<<<dim3((Sc * 32) / 256), dim3(256), 0, stream>>>(ct, st_);
    // 2. convert x + weights to bf16 (Wo keeps hi/lo)
    split_xw<<<dim3(4096, 5), dim3(256), 0, stream>>>(x, Wq, Wk, Wv, Wo, xh, whAll, wlAll);
    // 3. QKV projections (1-product bf16, dbuf) with fused epilogues
    gemm_qkv<<<dim3(32, 8, 3), dim3(256), 0, stream>>>(
        xh, whAll, Qh, Kh, Vh, ct, st_);
    // 4. attention (64q/block, 4 blocks/CU, all-K=32 MFMA) -> AOh/AOl
    attn7<<<dim3(1024), dim3(128), 0, stream>>>(Qh, Kh, Vh, AOh, AOl);
    // 5. output projection (3-product, 128x128 tiles)
    gemm_out<<<dim3(32, 8), dim3(256), 0, stream>>>(
        AOh, AOl, whAll + 3 * (1 << 20), wlAll + 3 * (1 << 20), out);
}

// Round 2
// 249.800 us; speedup vs baseline: 1.0067x; 1.0003x over previous
//
#include <hip/hip_runtime.h>
#include <math.h>

// Problem constants
constexpr int Bc = 2;
constexpr int Sc = 2048;
constexpr int Dc = 1024;
constexpr int Hc = 16;
constexpr int HDc = 64;

// Q pre-scale: attention 1/sqrt(64) folded with log2(e) for exp2-domain softmax
constexpr float QSC = 0.125f * 1.4426950408889634f;

typedef __attribute__((ext_vector_type(8))) short bf16x8;
typedef __attribute__((ext_vector_type(4))) float f32x4;
typedef __attribute__((ext_vector_type(4))) unsigned short us4;
typedef __attribute__((ext_vector_type(2))) unsigned int u32x2;
typedef __attribute__((ext_vector_type(4))) unsigned int u32x4;

// fp32 -> bf16 round-to-nearest-even (returns low 16 bits)
__device__ __forceinline__ unsigned f2bf(float x) {
    unsigned u = __float_as_uint(x);
    return (u + 0x7FFFu + ((u >> 16) & 1u)) >> 16;
}

__device__ __forceinline__ void split2(float x, unsigned short& h, unsigned short& l) {
    unsigned hh = f2bf(x);
    h = (unsigned short)hh;
    l = (unsigned short)f2bf(x - __uint_as_float(hh << 16));
}

// gfx950 cross-lane half-swaps: a=vdst, b=src; both updated.
#if __has_builtin(__builtin_amdgcn_permlane32_swap)
__device__ __forceinline__ void plswap32(unsigned& a, unsigned& b) {
    u32x2 r = __builtin_amdgcn_permlane32_swap(a, b, false, false);
    a = r.x; b = r.y;
}
#else
__device__ __forceinline__ void plswap32(unsigned& a, unsigned& b) {
    asm volatile("v_permlane32_swap_b32 %0, %1" : "+v"(a), "+v"(b));
}
#endif
#if __has_builtin(__builtin_amdgcn_permlane16_swap)
__device__ __forceinline__ void plswap16(unsigned& a, unsigned& b) {
    u32x2 r = __builtin_amdgcn_permlane16_swap(a, b, false, false);
    a = r.x; b = r.y;
}
#else
__device__ __forceinline__ void plswap16(unsigned& a, unsigned& b) {
    asm volatile("v_permlane16_swap_b32 %0, %1" : "+v"(a), "+v"(b));
}
#endif

// exp2 of 4 S-values, packed (truncating) into two bf16-pair words:
// w0 = {bf16(s0) lo, bf16(s1) hi}, w1 = {bf16(s2) lo, bf16(s3) hi}
__device__ __forceinline__ void exppack(const f32x4& sv, unsigned& w0, unsigned& w1) {
    unsigned u0 = __float_as_uint(__builtin_amdgcn_exp2f(sv[0]));
    unsigned u1 = __float_as_uint(__builtin_amdgcn_exp2f(sv[1]));
    unsigned u2 = __float_as_uint(__builtin_amdgcn_exp2f(sv[2]));
    unsigned u3 = __float_as_uint(__builtin_amdgcn_exp2f(sv[3]));
    w0 = __builtin_amdgcn_perm(u1, u0, 0x07060302u);
    w1 = __builtin_amdgcn_perm(u3, u2, 0x07060302u);
}

// ---------------------------------------------------------------------------
// RoPE cos/sin table: [S][32] each, double precision angles.
// ---------------------------------------------------------------------------
__global__ void rope_table(float* __restrict__ ct, float* __restrict__ st_) {
    int id = blockIdx.x * 256 + threadIdx.x;
    int s = id >> 5;
    int i = id & 31;
    double invf = pow(10000.0, -(double)i / 32.0);
    double ang = (double)s * invf;
    ct[id] = (float)cos(ang);
    st_[id] = (float)sin(ang);
}

// ---------------------------------------------------------------------------
// Convert: x -> bf16 hi; Wq/Wk/Wv -> hi; Wo -> hi + lo.
// ---------------------------------------------------------------------------
__global__ void split_xw(const float* __restrict__ x,
                         const float* __restrict__ Wq, const float* __restrict__ Wk,
                         const float* __restrict__ Wv, const float* __restrict__ Wo,
                         unsigned short* __restrict__ xh,
                         unsigned short* __restrict__ whAll, unsigned short* __restrict__ wlAll) {
    int y = blockIdx.y;
    const float* src;
    unsigned short* h;
    unsigned short* l = nullptr;
    int n;
    if (y == 0) { src = x; h = xh; n = 1 << 22; }
    else {
        src = (y == 1) ? Wq : (y == 2) ? Wk : (y == 3) ? Wv : Wo;
        h = whAll + (size_t)(y - 1) * (1 << 20);
        if (y == 4) l = wlAll + (size_t)3 * (1 << 20);
        n = 1 << 20;
    }
    int i = (blockIdx.x * 256 + threadIdx.x) * 4;
    if (i >= n) return;
    float4 v = *(const float4*)(src + i);
    us4 hh;
    ((unsigned short*)&hh)[0] = (unsigned short)f2bf(v.x);
    ((unsigned short*)&hh)[1] = (unsigned short)f2bf(v.y);
    ((unsigned short*)&hh)[2] = (unsigned short)f2bf(v.z);
    ((unsigned short*)&hh)[3] = (unsigned short)f2bf(v.w);
    *(us4*)(h + i) = hh;
    if (l) {
        us4 ll;
        const float* vp = (const float*)&v;
#pragma unroll
        for (int e = 0; e < 4; e++) {
            unsigned short hi = ((unsigned short*)&hh)[e];
            ((unsigned short*)&ll)[e] =
                (unsigned short)f2bf(vp[e] - __uint_as_float((unsigned)hi << 16));
        }
        *(us4*)(l + i) = ll;
    }
}

// ---------------------------------------------------------------------------
// QKV GEMM, bf16 1-product, 128x128 tile, BK=32, TRIPLE-buffered LDS with
// depth-2 prefetch + counted vmcnt (no full drain in main loop). m-fastest.
// Epilogues: z=0 Q (RoPE+QSC row-major), z=1 K (RoPE, [T][kb][tok][8] cells),
//            z=2 V (V^T cells [T][kk(2)][qd(4)][d(64)][tok8] — native K=32
//                   A-operand layout for attention PV)
// ---------------------------------------------------------------------------
__global__ __launch_bounds__(256) void gemm_qkv(
    const unsigned short* __restrict__ Ah,
    const unsigned short* __restrict__ whAll,
    unsigned short* __restrict__ Qh,
    unsigned short* __restrict__ Kh,
    unsigned short* __restrict__ Vh,
    const float* __restrict__ ct, const float* __restrict__ st_) {
    constexpr int K = 1024;
    __shared__ __align__(16) unsigned short AsH[3 * 4096], BsH[3 * 4096];

    const int z = blockIdx.z;
    const unsigned short* Wh = whAll + (size_t)z * (1 << 20);

    const int t = threadIdx.x;
    const int lane = t & 63;
    const int wave = t >> 6;
    const int l = lane & 15;
    const int quad = lane >> 4;
    const int wr = wave >> 1, wc = wave & 1;
    const int m0 = blockIdx.x * 128;
    const int n0 = blockIdx.y * 128;

    const int s_tensor = wave >> 1;
    const int s_rb = wave & 1;
    unsigned short* larr = s_tensor ? BsH : AsH;
    const unsigned short* gbase =
        (s_tensor ? Wh + (size_t)(n0 + s_rb * 64 + lane) * K
                  : Ah + (size_t)(m0 + s_rb * 64 + lane) * K);

    f32x4 acc[4][4];
#pragma unroll
    for (int i = 0; i < 4; i++)
#pragma unroll
        for (int j = 0; j < 4; j++) acc[i][j] = (f32x4){0.f, 0.f, 0.f, 0.f};

    // prologue: tiles 0 and 1 into buffers 0 and 1 (4 loads each)
#pragma unroll
    for (int q = 0; q < 4; q++)
        __builtin_amdgcn_global_load_lds(
            (const __attribute__((address_space(1))) unsigned int*)(gbase + q * 8),
            (__attribute__((address_space(3))) unsigned int*)(larr + (q * 128 + s_rb * 64) * 8),
            16, 0, 0);
#pragma unroll
    for (int q = 0; q < 4; q++)
        __builtin_amdgcn_global_load_lds(
            (const __attribute__((address_space(1))) unsigned int*)(gbase + 32 + q * 8),
            (__attribute__((address_space(3))) unsigned int*)(larr + 4096 + (q * 128 + s_rb * 64) * 8),
            16, 0, 0);

    int cb = 0;   // compute-buffer index == it % 3
    for (int it = 0; it < 32; ++it) {
        // wait for tile `it` (4 oldest loads) + drain own ds_reads, then sync
        if (it + 1 < 32)
            asm volatile("s_waitcnt vmcnt(4) lgkmcnt(0)\n\ts_barrier" ::: "memory");
        else
            asm volatile("s_waitcnt vmcnt(0) lgkmcnt(0)\n\ts_barrier" ::: "memory");

        if (it + 2 < 32) {
            int pb = cb + 2; if (pb >= 3) pb -= 3;   // (it+2) % 3
            const unsigned short* g = gbase + (it + 2) * 32;
            unsigned short* buf = larr + pb * 4096;
#pragma unroll
            for (int q = 0; q < 4; q++)
                __builtin_amdgcn_global_load_lds(
                    (const __attribute__((address_space(1))) unsigned int*)(g + q * 8),
                    (__attribute__((address_space(3))) unsigned int*)(buf + (q * 128 + s_rb * 64) * 8),
                    16, 0, 0);
        }
        const unsigned short* a = AsH + cb * 4096;
        const unsigned short* bb = BsH + cb * 4096;
        bf16x8 ah[4], bh[4];
#pragma unroll
        for (int i = 0; i < 4; i++) {
            ah[i] = *(const bf16x8*)&a[(quad * 128 + wr * 64 + i * 16 + l) * 8];
            bh[i] = *(const bf16x8*)&bb[(quad * 128 + wc * 64 + i * 16 + l) * 8];
        }
#pragma unroll
        for (int i = 0; i < 4; i++)
#pragma unroll
            for (int j = 0; j < 4; j++)
                acc[i][j] = __builtin_amdgcn_mfma_f32_16x16x32_bf16(ah[i], bh[j], acc[i][j], 0, 0, 0);
        if (++cb == 3) cb = 0;
    }

    // ---- fused epilogue ----
    const int hcol = ((n0 + wc * 64) >> 6);   // head index 0..15
    if (z == 2) {
        // V^T cells, K=32 A-operand layout:
        //   off = ((kk*4 + qd)*64 + d)*8 + tj, tok64 = kk*32 + qd*8 + tj
        // acc[i][jj][r]: tok64 = i*16 + quad*4 + r, d = jj*16 + l
#pragma unroll
        for (int i = 0; i < 4; i++) {
            int m_base = m0 + wr * 64 + i * 16 + quad * 4;
            int bbk = m_base >> 11;
            int T = (m_base & (Sc - 1)) >> 6;
            int kk = i >> 1;
            int qd = ((i & 1) << 1) | (quad >> 1);
            int tj = (quad & 1) * 4;
            size_t tilebase = (((size_t)(bbk * Hc + hcol)) * 32 + T) * 4096;
#pragma unroll
            for (int jj = 0; jj < 4; jj++) {
                int d = jj * 16 + l;
                size_t off = tilebase + (size_t)(((kk * 4 + qd) * 64 + d) * 8 + tj);
                us4 v4;
#pragma unroll
                for (int r = 0; r < 4; r++)
                    ((unsigned short*)&v4)[r] = (unsigned short)f2bf(acc[i][jj][r]);
                *(us4*)(Vh + off) = v4;
            }
        }
    } else {
#pragma unroll
        for (int i = 0; i < 4; i++)
#pragma unroll
            for (int r = 0; r < 4; r++) {
                int m = m0 + wr * 64 + i * 16 + quad * 4 + r;
                int bbk = m >> 11, s = m & (Sc - 1);
#pragma unroll
                for (int jp = 0; jp < 2; jp++) {
                    int d = jp * 16 + l;                       // 0..31
                    float cs = ct[s * 32 + d];
                    float sn = st_[s * 32 + d];
                    float x0 = acc[i][jp][r];
                    float x1 = acc[i][jp + 2][r];
                    float y0 = x0 * cs - x1 * sn;
                    float y1 = x1 * cs + x0 * sn;
                    if (z == 0) {
                        size_t rowb = (((size_t)(bbk * Hc + hcol)) * Sc + s) * HDc;
                        Qh[rowb + d]      = (unsigned short)f2bf(y0 * QSC);
                        Qh[rowb + d + 32] = (unsigned short)f2bf(y1 * QSC);
                    } else {
                        int T = s >> 6, tok = s & 63;
                        size_t tb = (((size_t)(bbk * Hc + hcol)) * 32 + T) * 8;
                        size_t off0 = ((tb + (d >> 3)) * 64 + tok) * 8 + (d & 7);
                        size_t off1 = ((tb + (d >> 3) + 4) * 64 + tok) * 8 + (d & 7);
                        Kh[off0] = (unsigned short)f2bf(y0);
                        Kh[off1] = (unsigned short)f2bf(y1);
                    }
                }
            }
    }
}

// ---------------------------------------------------------------------------
// MFMA flash attention v8: all-K=32 MFMA.
// 64 q/block, 2 waves x 2 bands -> grid 1024 = 4 blocks/CU.
// P^T K=32 B-fragments built in-register via permlane32/16_swap; PV and
// row-sum use mfma_f32_16x16x32_bf16 (no legacy K=16 MFMA anywhere).
// ---------------------------------------------------------------------------
__global__ __launch_bounds__(128) void attn7(
    const unsigned short* __restrict__ Qh,
    const unsigned short* __restrict__ Kh,
    const unsigned short* __restrict__ Vh,
    unsigned short* __restrict__ AOh, unsigned short* __restrict__ AOl) {
    __shared__ __align__(16) unsigned short KsH[2 * 4096], VtH[2 * 4096];

    const int t = threadIdx.x;
    const int lane = t & 63;
    const int wave = t >> 6;               // 0..1
    const int l = lane & 15;
    const int quad = lane >> 4;
    const int id = blockIdx.x;             // 0..1023
    const int bh = (id & 7) * 4 + (id >> 8);   // XCD-clustered (4 bh / XCD)
    const int qt = (id >> 3) & 31;
    const int q0 = qt * 64;
    const int b = bh >> 4;
    const int hh = bh & 15;

    const bf16x8 ONES8 = {(short)0x3F80, (short)0x3F80, (short)0x3F80, (short)0x3F80,
                          (short)0x3F80, (short)0x3F80, (short)0x3F80, (short)0x3F80};

    // Q fragments (B operand: n=q=lane&15, k=d=quad*8+j); band bnd -> rows
    // q0 + bnd*32 + wave*16 + l
    bf16x8 qf[2][2];
#pragma unroll
    for (int bnd = 0; bnd < 2; bnd++) {
        size_t rowb = ((size_t)bh * Sc + q0 + bnd * 32 + wave * 16 + l) * HDc;
#pragma unroll
        for (int ks = 0; ks < 2; ks++)
            qf[bnd][ks] = *(const bf16x8*)(Qh + rowb + ks * 32 + quad * 8);
    }

    f32x4 o[2][4], lac[2];
#pragma unroll
    for (int bnd = 0; bnd < 2; bnd++) {
        lac[bnd] = (f32x4){0.f, 0.f, 0.f, 0.f};
#pragma unroll
        for (int i = 0; i < 4; i++) o[bnd][i] = (f32x4){0.f, 0.f, 0.f, 0.f};
    }

    // staging: wave 0 -> K, wave 1 -> V; 8 chunks of 512 elems each.
    unsigned short* larr = wave ? VtH : KsH;
    const unsigned short* gB = (wave ? Vh : Kh) + (size_t)bh * Sc * HDc + lane * 8;

#pragma unroll
    for (int q = 0; q < 8; q++)
        __builtin_amdgcn_global_load_lds(
            (const __attribute__((address_space(1))) unsigned int*)(gB + q * 512),
            (__attribute__((address_space(3))) unsigned int*)(larr + q * 512),
            16, 0, 0);

    for (int kt = 0; kt < 32; kt++) {
        __syncthreads();
        if (kt + 1 < 32) {
            const unsigned short* g = gB + (size_t)(kt + 1) * 4096;
            unsigned short* buf = larr + ((kt + 1) & 1) * 4096;
#pragma unroll
            for (int q = 0; q < 8; q++)
                __builtin_amdgcn_global_load_lds(
                    (const __attribute__((address_space(1))) unsigned int*)(g + q * 512),
                    (__attribute__((address_space(3))) unsigned int*)(buf + q * 512),
                    16, 0, 0);
        }
        const unsigned short* Kbuf = KsH + (kt & 1) * 4096;
        const unsigned short* Vbuf = VtH + (kt & 1) * 4096;

        // ---- S^T = K @ Q^T: A=K frag (m=tok), B=Q frag (n=q) ----
        f32x4 s[2][4];
#pragma unroll
        for (int bnd = 0; bnd < 2; bnd++)
#pragma unroll
            for (int tt = 0; tt < 4; tt++) s[bnd][tt] = (f32x4){0.f, 0.f, 0.f, 0.f};
#pragma unroll
        for (int ks = 0; ks < 2; ks++)
#pragma unroll
            for (int tt = 0; tt < 4; tt++) {
                bf16x8 kf = *(const bf16x8*)&Kbuf[((ks * 4 + quad) * 64 + tt * 16 + l) * 8];
                s[0][tt] = __builtin_amdgcn_mfma_f32_16x16x32_bf16(kf, qf[0][ks], s[0][tt], 0, 0, 0);
                s[1][tt] = __builtin_amdgcn_mfma_f32_16x16x32_bf16(kf, qf[1][ks], s[1][tt], 0, 0, 0);
            }

        // ---- P^T = exp2(S^T), packed + permlane-transposed into K=32
        //      B-operand fragments (tokens quad*8+j contiguous per lane) ----
        bf16x8 pf[2][2];
#pragma unroll
        for (int bnd = 0; bnd < 2; bnd++)
#pragma unroll
            for (int ttp = 0; ttp < 2; ttp++) {
                unsigned A0, A1, B0, B1;
                exppack(s[bnd][2 * ttp], A0, A1);       // tokens ttp*32 + quad*4 + {0..3}
                exppack(s[bnd][2 * ttp + 1], B0, B1);   // tokens ttp*32 + 16 + quad*4 + {0..3}
                plswap32(A0, B0);   // A0: q01=A0@q01, q23=B0@q01 ; B0: q01=A0@q23, q23=B0@q23
                plswap16(A0, B0);   // A0 -> frag word0, B0 -> frag word2
                plswap32(A1, B1);
                plswap16(A1, B1);   // A1 -> frag word1, B1 -> frag word3
                u32x4 fw = {A0, A1, B0, B1};
                bf16x8 p8 = __builtin_bit_cast(bf16x8, fw);
                pf[bnd][ttp] = p8;
                lac[bnd] = __builtin_amdgcn_mfma_f32_16x16x32_bf16(ONES8, p8, lac[bnd], 0, 0, 0);
            }

        // ---- O^T += V^T @ P^T (K=32; V frags shared across bands) ----
#pragma unroll
        for (int kk = 0; kk < 2; kk++)
#pragma unroll
            for (int dd = 0; dd < 4; dd++) {
                bf16x8 vf = *(const bf16x8*)
                    &Vbuf[(size_t)((kk * 4 + quad) * 64 + dd * 16 + l) * 8];
                o[0][dd] = __builtin_amdgcn_mfma_f32_16x16x32_bf16(vf, pf[0][kk], o[0][dd], 0, 0, 0);
                o[1][dd] = __builtin_amdgcn_mfma_f32_16x16x32_bf16(vf, pf[1][kk], o[1][dd], 0, 0, 0);
            }
    }

    // ---- epilogue: O^T frag: col q = lane&15, row d = dd*16 + quad*4 + r ----
#pragma unroll
    for (int bnd = 0; bnd < 2; bnd++) {
        float inv = 1.f / lac[bnd][0];   // all 4 regs equal (ONES-A rows identical)
        int q = q0 + bnd * 32 + wave * 16 + l;
        size_t rowb = ((size_t)b * Sc + q) * Dc + hh * HDc + quad * 4;
#pragma unroll
        for (int dd = 0; dd < 4; dd++) {
            us4 h4, l4;
#pragma unroll
            for (int r = 0; r < 4; r++)
                split2(o[bnd][dd][r] * inv,
                       ((unsigned short*)&h4)[r], ((unsigned short*)&l4)[r]);
            *(us4*)(AOh + rowb + dd * 16) = h4;
            *(us4*)(AOl + rowb + dd * 16) = l4;
        }
    }
}

// ---------------------------------------------------------------------------
// Output projection GEMM (MFMA split-bf16 3-product), 128x128, fp32 out.
// TRIPLE-buffered LDS (96 KB), depth-2 prefetch + counted vmcnt — grid is
// 1 block/CU (zero TLP), so all latency hiding must come from the pipeline.
// ---------------------------------------------------------------------------
__global__ __launch_bounds__(256) void gemm_out(
    const unsigned short* __restrict__ Ah, const unsigned short* __restrict__ Al,
    const unsigned short* __restrict__ Wh, const unsigned short* __restrict__ Wl,
    float* __restrict__ C) {
    constexpr int K = 1024;
    __shared__ __align__(16) unsigned short AsH[3 * 4096], AsL[3 * 4096],
                                            BsH[3 * 4096], BsL[3 * 4096];

    const int t = threadIdx.x;
    const int lane = t & 63;
    const int wave = t >> 6;
    const int l = lane & 15;
    const int quad = lane >> 4;
    const int wr = wave >> 1, wc = wave & 1;
    const int m0 = blockIdx.x * 128;   // m fastest -> XCD A-locality
    const int n0 = blockIdx.y * 128;

    // staging: wave 0 = A-hi, 1 = A-lo, 2 = B-hi, 3 = B-lo; 8 jobs each.
    unsigned short* larr = (wave == 0) ? AsH : (wave == 1) ? AsL : (wave == 2) ? BsH : BsL;
    const unsigned short* garr = (wave == 0) ? Ah : (wave == 1) ? Al : (wave == 2) ? Wh : Wl;
    const int t0 = (wave < 2) ? m0 : n0;

    const unsigned short* gsrc[8];
    int ldst[8];
#pragma unroll
    for (int q = 0; q < 8; q++) {
        int rb = q >> 2;
        int kb = q & 3;
        gsrc[q] = garr + (size_t)(t0 + rb * 64 + lane) * K + kb * 8;
        ldst[q] = (kb * 128 + rb * 64) * 8;
    }

    f32x4 acc[4][4];
#pragma unroll
    for (int i = 0; i < 4; i++)
#pragma unroll
        for (int j = 0; j < 4; j++) acc[i][j] = (f32x4){0.f, 0.f, 0.f, 0.f};

    // prologue: tiles 0 and 1 into buffers 0 and 1 (8 loads each)
#pragma unroll
    for (int q = 0; q < 8; q++)
        __builtin_amdgcn_global_load_lds(
            (const __attribute__((address_space(1))) unsigned int*)gsrc[q],
            (__attribute__((address_space(3))) unsigned int*)(larr + ldst[q]), 16, 0, 0);
#pragma unroll
    for (int q = 0; q < 8; q++)
        __builtin_amdgcn_global_load_lds(
            (const __attribute__((address_space(1))) unsigned int*)(gsrc[q] + 32),
            (__attribute__((address_space(3))) unsigned int*)(larr + 4096 + ldst[q]), 16, 0, 0);

    int cb = 0;   // compute-buffer index == it % 3
    for (int it = 0; it < 32; ++it) {
        if (it + 1 < 32)
            asm volatile("s_waitcnt vmcnt(8) lgkmcnt(0)\n\ts_barrier" ::: "memory");
        else
            asm volatile("s_waitcnt vmcnt(0) lgkmcnt(0)\n\ts_barrier" ::: "memory");

        if (it + 2 < 32) {
            int pb = cb + 2; if (pb >= 3) pb -= 3;   // (it+2) % 3
            unsigned short* buf = larr + pb * 4096;
            int koff = (it + 2) * 32;
#pragma unroll
            for (int q = 0; q < 8; q++)
                __builtin_amdgcn_global_load_lds(
                    (const __attribute__((address_space(1))) unsigned int*)(gsrc[q] + koff),
                    (__attribute__((address_space(3))) unsigned int*)(buf + ldst[q]), 16, 0, 0);
        }
        const int bo = cb * 4096;
        bf16x8 ah[4], al[4], bh[4], bl[4];
#pragma unroll
        for (int i = 0; i < 4; i++) {
            int ra = bo + (quad * 128 + wr * 64 + i * 16 + l) * 8;
            ah[i] = *(const bf16x8*)&AsH[ra];
            al[i] = *(const bf16x8*)&AsL[ra];
            int rb2 = bo + (quad * 128 + wc * 64 + i * 16 + l) * 8;
            bh[i] = *(const bf16x8*)&BsH[rb2];
            bl[i] = *(const bf16x8*)&BsL[rb2];
        }
#pragma unroll
        for (int i = 0; i < 4; i++)
#pragma unroll
            for (int j = 0; j < 4; j++) {
                acc[i][j] = __builtin_amdgcn_mfma_f32_16x16x32_bf16(ah[i], bh[j], acc[i][j], 0, 0, 0);
                acc[i][j] = __builtin_amdgcn_mfma_f32_16x16x32_bf16(al[i], bh[j], acc[i][j], 0, 0, 0);
                acc[i][j] = __builtin_amdgcn_mfma_f32_16x16x32_bf16(ah[i], bl[j], acc[i][j], 0, 0, 0);
            }
        if (++cb == 3) cb = 0;
    }

#pragma unroll
    for (int i = 0; i < 4; i++)
#pragma unroll
        for (int j = 0; j < 4; j++)
#pragma unroll
            for (int r = 0; r < 4; r++) {
                int m = m0 + wr * 64 + i * 16 + quad * 4 + r;
                int n = n0 + wc * 64 + j * 16 + l;
                C[(size_t)m * Dc + n] = acc[i][j][r];
            }
}

// ---------------------------------------------------------------------------
extern "C" void kernel_launch(void* const* d_in, const int* in_sizes, int n_in,
                              void* d_out, int out_size, void* d_ws, size_t ws_size,
                              hipStream_t stream) {
    const float* x  = (const float*)d_in[0];
    const float* Wq = (const float*)d_in[1];
    const float* Wk = (const float*)d_in[2];
    const float* Wv = (const float*)d_in[3];
    const float* Wo = (const float*)d_in[4];
    float* out = (float*)d_out;

    unsigned short* usw = (unsigned short*)d_ws;
    const size_t M4 = (size_t)1 << 22;   // 4M elements
    unsigned short* whAll = usw;                 // 4 x 1M weights hi
    unsigned short* wlAll = usw + M4;            // lo (only Wo slot used)
    unsigned short* xh = usw + 2 * M4;           // x hi (later AOh)
    unsigned short* xl = usw + 3 * M4;           // later AOl
    unsigned short* Qh = usw + 4 * M4;
    unsigned short* Kh = usw + 5 * M4;
    unsigned short* Vh = usw + 6 * M4;
    float* ct = (float*)(usw + 7 * M4);
    float* st_ = ct + (size_t)Sc * 32;
    unsigned short* AOh = xh;   // x dead after QKV GEMM
    unsigned short* AOl = xl;

    // 1. RoPE table
    rope_table<<<dim3((Sc * 32) / 256), dim3(256), 0, stream>>>(ct, st_);
    // 2. convert x + weights to bf16 (Wo keeps hi/lo)
    split_xw<<<dim3(4096, 5), dim3(256), 0, stream>>>(x, Wq, Wk, Wv, Wo, xh, whAll, wlAll);
    // 3. QKV projections (depth-2 pipelined) with fused epilogues
    gemm_qkv<<<dim3(32, 8, 3), dim3(256), 0, stream>>>(
        xh, whAll, Qh, Kh, Vh, ct, st_);
    // 4. attention (64q/block, 4 blocks/CU, all-K=32 MFMA) -> AOh/AOl
    attn7<<<dim3(1024), dim3(128), 0, stream>>>(Qh, Kh, Vh, AOh, AOl);
    // 5. output projection (depth-2 pipelined, 3-product, 128x128 tiles)
    gemm_out<<<dim3(32, 8), dim3(256), 0, stream>>>(
        AOh, AOl, whAll + 3 * (1 << 20), wlAll + 3 * (1 << 20), out);
}